// Round 1
// 212960.303 us; speedup vs baseline: 1.3385x; 1.3385x over previous
//
#include <hip/hip_runtime.h>
#include <hip/hip_bf16.h>

// Decoder_62079457296567 — Tacotron2-style decoder, B=64 T_enc=300 T_dec=500 D=512 MEL=80 PRE=256
// Round 8: attack the 93% latency-stall (VALUBusy 6%, all pipes idle).
//  - LSTM weights persisted in LDS per block (att 80KB / dec 96KB dynamic LDS) — fence-immune,
//    no per-step LLC refetch of the 22 MB/step weight set.
//  - X operands re-laid-out as [k/4][b][4] so dot loops do one coalesced float4/4k (4x fewer loads).
//  - conv weights+bias, melw/stopw/w1/w2 rows in LDS; biases in registers.
//  - h_att staged to LDS via transposed g_hattT; a/a_cum staged padded (branch-free conv).
//  - mel input transposed at convert ([t][m][b]) -> pre1 coalesced.
//  - d-pairing (da,da+1) -> float2 loads for qwT/memwt.
// Barrier structure unchanged: flag/relay grid barrier, 3 barriers/step, 256 blocks co-resident.

#define DEV __device__ __forceinline__
typedef __hip_bfloat16 bf16;
DEV float b2f(bf16 x) { return __bfloat162float(x); }
DEV unsigned short f2us(float f) { bf16 h = __float2bfloat16(f); unsigned short u; __builtin_memcpy(&u, &h, 2); return u; }
DEV float us2f(unsigned short u) { union { float f; unsigned int i; } c; c.i = ((unsigned)u) << 16; return c.f; }

constexpr int NB = 256;
constexpr int DYN_BYTES = 98304;   // dec blocks: 16*1024 + 16*512 floats = 96 KB

// ---------------- canonical fp32 inputs (device .bss) ----------------
__device__ float g_enc[64*300*512];
__device__ __align__(16) float g_melT[500*80*64];   // [t][m][b]
__device__ float g_w1[256*80];
__device__ float g_b1[256];
__device__ float g_w2[256*256];
__device__ float g_b2[256];
__device__ float g_awih[2048*768];
__device__ float g_awhh[2048*512];
__device__ float g_ab[2048];
__device__ float g_dwih[2048*1024];
__device__ float g_dwhh[2048*512];
__device__ float g_db[2048];
__device__ float g_qwt[512*512];     // q_w^T [k][d]
__device__ float g_qpb[512];
__device__ float g_memwt[512*512];   // mem_w^T [k][d]
__device__ float g_memb[512];
__device__ float g_cw[32*62];
__device__ float g_cb[32];
__device__ float g_pw[512*32];
__device__ float g_vw[512];
__device__ float g_melw[80*512];
__device__ float g_melb[80];
__device__ float g_stopw[512];
__device__ float g_scal[2];          // v_b, stop_b
__device__ int   g_f32io;
// ---------------- recurrent state (X4 layout: [k>>2][b][k&3]) ----------------
__device__ __align__(16) float g_hatt4[2*512*64];
__device__ __align__(16) float g_hattT[64*512];     // [b][k] for q staging
__device__ float g_catt[512*64];
__device__ __align__(16) float g_hdec4[2*512*64];
__device__ float g_cdec[512*64];
__device__ __align__(16) float g_ctx4[512*64];
__device__ float g_a[64*300];
__device__ float g_acum[64*300];
__device__ __align__(16) float g_pmt4[256*64];
__device__ __align__(16) float g_pm1t4[256*64];
__device__ float g_e[64*300];
// ---------------- barrier (flag relay; zeroed by k_convert each launch) ----------------
__device__ int g_flag[NB*32];
__device__ int g_go[16*32];

struct InPtrs { const void* p[28]; };

DEV float sigf(float x) { return 1.f / (1.f + __expf(-x)); }
DEV float tanhf_fast(float x) {
  float e = __expf(-2.f * fabsf(x));
  float r = (1.f - e) / (1.f + e);
  return copysignf(r, x);
}

DEV int detect_f32(const void* enc_raw) {
  const unsigned short* u = (const unsigned short*)enc_raw;
  int big = 0;
  for (int i = 0; i < 256; i += 2) { int e = (u[i] >> 7) & 0xFF; big += (e > 133) ? 1 : 0; }
  return big >= 8 ? 1 : 0;
}
DEV float ldin(const void* p, int i, int f32) {
  return f32 ? ((const float*)p)[i] : b2f(((const bf16*)p)[i]);
}

// ---------------- conversion kernel (also zeroes state + barrier) ----------------
__global__ __launch_bounds__(256) void k_convert(InPtrs P) {
  const int NT = gridDim.x * 256;
  const int flat = blockIdx.x * 256 + threadIdx.x;
  const int f32 = detect_f32(P.p[0]);
  if (flat == 0) {
    g_f32io = f32;
    g_scal[0] = ldin(P.p[23], 0, f32);
    g_scal[1] = ldin(P.p[27], 0, f32);
  }
#define CVT(dst, idx, n) for (int i = flat; i < (n); i += NT) dst[i] = ldin(P.p[idx], i, f32);
  CVT(g_enc, 0, 64*300*512)
  CVT(g_w1, 2, 256*80)   CVT(g_b1, 3, 256)
  CVT(g_w2, 4, 256*256)  CVT(g_b2, 5, 256)
  CVT(g_awih, 6, 2048*768)  CVT(g_awhh, 7, 2048*512)
  CVT(g_dwih, 10, 2048*1024) CVT(g_dwhh, 11, 2048*512)
  CVT(g_cw, 18, 32*62) CVT(g_cb, 19, 32)
  CVT(g_pw, 20, 512*32)  CVT(g_vw, 22, 512)
  CVT(g_melw, 24, 80*512) CVT(g_melb, 25, 80)
  CVT(g_stopw, 26, 512)  CVT(g_memb, 17, 512)
#undef CVT
  // mel transpose: g_melT[(t*80+m)*64 + b] = mel[b][t][m]
  for (int i = flat; i < 500*80*64; i += NT) {
    int b = i & 63, tm = i >> 6;
    g_melT[i] = ldin(P.p[1], b*40000 + tm, f32);
  }
  for (int i = flat; i < 2048; i += NT) g_ab[i] = ldin(P.p[8], i, f32) + ldin(P.p[9], i, f32);
  for (int i = flat; i < 2048; i += NT) g_db[i] = ldin(P.p[12], i, f32) + ldin(P.p[13], i, f32);
  for (int i = flat; i < 512; i += NT) g_qpb[i] = ldin(P.p[15], i, f32) + ldin(P.p[21], i, f32);
  for (int o = flat; o < 512*512; o += NT) {
    int d = o >> 9, k = o & 511;
    g_memwt[(size_t)k*512 + d] = ldin(P.p[16], o, f32);
    g_qwt[(size_t)k*512 + d]   = ldin(P.p[14], o, f32);
  }
  // zero state + barrier
  for (int i = flat; i < 2*512*64; i += NT) { g_hatt4[i] = 0.f; g_hdec4[i] = 0.f; }
  for (int i = flat; i < 512*64; i += NT) { g_catt[i] = 0.f; g_cdec[i] = 0.f; g_ctx4[i] = 0.f; }
  for (int i = flat; i < 64*512; i += NT) g_hattT[i] = 0.f;
  for (int i = flat; i < 64*300; i += NT) { g_a[i] = 0.f; g_acum[i] = 0.f; }
  for (int i = flat; i < NB*32; i += NT) g_flag[i] = 0;
  for (int i = flat; i < 16*32; i += NT) g_go[i] = 0;
}

// ---------------- flag/relay grid barrier ----------------
DEV void gbar(int n, int bb, int tid) {
  __syncthreads();
  if (tid == 0) {
    __threadfence();
    __hip_atomic_store(&g_flag[bb*32], n, __ATOMIC_RELAXED, __HIP_MEMORY_SCOPE_AGENT);
  }
  if (bb == 0) {
    while (__hip_atomic_load(&g_flag[tid*32], __ATOMIC_RELAXED, __HIP_MEMORY_SCOPE_AGENT) < n)
      __builtin_amdgcn_s_sleep(1);
    __syncthreads();
    if (tid == 0) __threadfence();
    __syncthreads();
    if (tid < 16)
      __hip_atomic_store(&g_go[tid*32], n, __ATOMIC_RELAXED, __HIP_MEMORY_SCOPE_AGENT);
  } else {
    if (tid == 0) {
      while (__hip_atomic_load(&g_go[(bb>>4)*32], __ATOMIC_RELAXED, __HIP_MEMORY_SCOPE_AGENT) < n)
        __builtin_amdgcn_s_sleep(1);
      __threadfence();
    }
  }
  __syncthreads();
}

// 4 simultaneous dots: weights are LDS row pointers (uniform-address ds_read_b128 broadcast),
// X is global in [k>>2][b][k&3] layout so each lane does one coalesced float4 per 4 k.
DEV void dot4(const float* __restrict__ X4, int n,
              const float* __restrict__ w0, const float* __restrict__ w1,
              const float* __restrict__ w2, const float* __restrict__ w3,
              int lane, float& a0, float& a1, float& a2, float& a3) {
  const float* xp = X4 + lane*4;
#pragma unroll 4
  for (int k = 0; k < n; k += 4) {
    float4 x  = *(const float4*)(xp + k*64);
    float4 u0 = *(const float4*)(w0 + k);
    float4 u1 = *(const float4*)(w1 + k);
    float4 u2 = *(const float4*)(w2 + k);
    float4 u3 = *(const float4*)(w3 + k);
    a0 = fmaf(u0.x,x.x,a0); a0 = fmaf(u0.y,x.y,a0); a0 = fmaf(u0.z,x.z,a0); a0 = fmaf(u0.w,x.w,a0);
    a1 = fmaf(u1.x,x.x,a1); a1 = fmaf(u1.y,x.y,a1); a1 = fmaf(u1.z,x.z,a1); a1 = fmaf(u1.w,x.w,a1);
    a2 = fmaf(u2.x,x.x,a2); a2 = fmaf(u2.y,x.y,a2); a2 = fmaf(u2.z,x.z,a2); a2 = fmaf(u2.w,x.w,a2);
    a3 = fmaf(u3.x,x.x,a3); a3 = fmaf(u3.y,x.y,a3); a3 = fmaf(u3.z,x.z,a3); a3 = fmaf(u3.w,x.w,a3);
  }
}

__global__ __launch_bounds__(256) void k_dec(void* outv) {
  const int bb = blockIdx.x;
  const int tid = threadIdx.x;
  const int lane = tid & 63, wv = tid >> 6;
  const int f32io = g_f32io;
  bf16* outh = (bf16*)outv;
  float* outf = (float*)outv;

  extern __shared__ float dyn[];                 // persistent LSTM weights
  __shared__ float sbuf[2432];
  __shared__ float part[4][76];
  __shared__ float s_h[512];                     // h_att[eb] for q-dot
  __shared__ float s_aa[664];                    // padded a [0..330) / acum [332..662)
  __shared__ float s_cw[2016];                   // conv weights + bias @1984
  __shared__ __align__(16) float s_sm[2048];     // role weights: melw/stopw/w2/w1 rows

  const int eb = bb >> 2, tt0 = (bb & 3) * 75;
  const int da = wv*128 + lane*2;                // d-pair (da, da+1)
  int bn = 0;

  // ---- one-time LDS persist ----
  if (bb < 128) {
    for (int r = 0; r < 16; ++r) {
      const int grow = (r & 3)*512 + bb*4 + (r >> 2);       // gate*(512) + unit
      for (int c = tid; c < 768; c += 256) dyn[r*768 + c] = g_awih[(size_t)grow*768 + c];
      for (int c = tid; c < 512; c += 256) dyn[12288 + r*512 + c] = g_awhh[(size_t)grow*512 + c];
    }
  } else {
    for (int r = 0; r < 16; ++r) {
      const int grow = (r & 3)*512 + (bb - 128)*4 + (r >> 2);
      for (int c = tid; c < 1024; c += 256) dyn[r*1024 + c] = g_dwih[(size_t)grow*1024 + c];
      for (int c = tid; c < 512; c += 256) dyn[16384 + r*512 + c] = g_dwhh[(size_t)grow*512 + c];
    }
  }
  for (int i = tid; i < 1984; i += 256) s_cw[i] = g_cw[i];
  for (int i = tid; i < 32; i += 256) s_cw[1984 + i] = g_cb[i];
  if (bb < 20)                      { for (int i = tid; i < 2048; i += 256) s_sm[i] = g_melw[bb*2048 + i]; }
  else if (bb == 20)                { for (int i = tid; i < 512;  i += 256) s_sm[i] = g_stopw[i]; }
  else if (bb >= 64 && bb < 128)    { for (int i = tid; i < 1024; i += 256) s_sm[i] = g_w2[(bb-64)*1024 + i]; }
  else if (bb >= 192)               { for (int i = tid; i < 320;  i += 256) s_sm[i] = g_w1[(bb-192)*320 + i]; }
  for (int i = tid; i < 664; i += 256) s_aa[i] = 0.f;      // zero pads once
  __syncthreads();

  // per-wave / per-role register preloads
  const int jrow = __builtin_amdgcn_readfirstlane((bb < 128 ? bb*4 : (bb-128)*4) + wv);
  float bi, bfg, bgg, bog;
  if (bb < 128) { bi = g_ab[jrow]; bfg = g_ab[512+jrow]; bgg = g_ab[1024+jrow]; bog = g_ab[1536+jrow]; }
  else          { bi = g_db[jrow]; bfg = g_db[512+jrow]; bgg = g_db[1024+jrow]; bog = g_db[1536+jrow]; }
  float prb = 0.f;
  if (bb < 20) prb = g_melb[bb*4 + wv];
  else if (bb >= 64 && bb < 128) prb = g_b2[(bb-64)*4 + wv];
  else if (bb >= 192) prb = g_b1[(bb-192)*4 + wv];

  // ---- Pr0: pre1(0) on blocks 192..255 ----
  if (bb >= 192) {
    float acc = prb;
    const float* mt = g_melT + lane;             // t=0
    const float* wr = s_sm + wv*80;
#pragma unroll 8
    for (int m = 0; m < 80; ++m) acc = fmaf(wr[m], mt[m*64], acc);
    g_pm1t4[(bb-192)*256 + lane*4 + wv] = fmaxf(acc, 0.f);
  }
  gbar(++bn, bb, tid);

  // ---- Pr1: mproj chunk -> registers (packed bf16x2); pre2(0) on blocks 64..127 ----
  unsigned int mpq[75];
  {
    float a1[75], a2[75];
#pragma unroll
    for (int r = 0; r < 75; ++r) { a1[r] = 0.f; a2[r] = 0.f; }
    for (int kt = 0; kt < 16; ++kt) {
      __syncthreads();
      for (int i = tid; i < 75*32; i += 256) {
        int r = i >> 5, kk = i & 31;
        sbuf[i] = g_enc[((size_t)eb*300 + tt0 + r)*512 + kt*32 + kk];
      }
      __syncthreads();
      for (int kk = 0; kk < 32; ++kk) {
        const int k = kt*32 + kk;
        const float2 w = *(const float2*)(g_memwt + (size_t)k*512 + da);
#pragma unroll
        for (int r = 0; r < 75; ++r) {
          const float ev = sbuf[r*32 + kk];
          a1[r] = fmaf(ev, w.x, a1[r]);
          a2[r] = fmaf(ev, w.y, a2[r]);
        }
      }
    }
    const float2 mb = *(const float2*)(g_memb + da);
#pragma unroll
    for (int r = 0; r < 75; ++r)
      mpq[r] = (unsigned)f2us(a1[r] + mb.x) | ((unsigned)f2us(a2[r] + mb.y) << 16);
    if (bb >= 64 && bb < 128) {      // pre2(0)
      float acc = prb;
      const float* wr = s_sm + wv*256;
      const float* xp = g_pm1t4 + lane*4;
#pragma unroll 4
      for (int k = 0; k < 256; k += 4) {
        float4 u = *(const float4*)(wr + k);
        float4 x = *(const float4*)(xp + k*64);
        acc = fmaf(u.x,x.x,acc); acc = fmaf(u.y,x.y,acc);
        acc = fmaf(u.z,x.z,acc); acc = fmaf(u.w,x.w,acc);
      }
      g_pmt4[(bb-64)*256 + lane*4 + wv] = fmaxf(acc, 0.f);
    }
  }
  float Pa[32], Pb[32];
#pragma unroll
  for (int i = 0; i < 8; ++i) {
    float4 u = *(const float4*)(g_pw + (size_t)da*32 + 4*i);
    float4 w = *(const float4*)(g_pw + (size_t)(da+1)*32 + 4*i);
    Pa[4*i] = u.x; Pa[4*i+1] = u.y; Pa[4*i+2] = u.z; Pa[4*i+3] = u.w;
    Pb[4*i] = w.x; Pb[4*i+1] = w.y; Pb[4*i+2] = w.z; Pb[4*i+3] = w.w;
  }
  const float2 vv  = *(const float2*)(g_vw + da);
  const float2 qb2 = *(const float2*)(g_qpb + da);
  const float v1 = vv.x, v2 = vv.y;
  const float vb = g_scal[0];
  gbar(++bn, bb, tid);

  // ================= main loop: 3 barriers/step =================
  for (int t = 0; t <= 500; ++t) {
    const int rp = t & 1, wp = rp ^ 1;

    // ---- P1: att-LSTM(t) [0..127] | dec-LSTM(t-1) [128..255] ----
    if (bb < 128) {
      if (t < 500) {
        float ai = bi, af = bfg, ag = bgg, ao = bog;
        const float* w0 = dyn + (wv*4 + 0)*768;
        const float* w1 = dyn + (wv*4 + 1)*768;
        const float* w2 = dyn + (wv*4 + 2)*768;
        const float* w3 = dyn + (wv*4 + 3)*768;
        dot4(g_pmt4, 256, w0, w1, w2, w3, lane, ai, af, ag, ao);
        dot4(g_ctx4, 512, w0+256, w1+256, w2+256, w3+256, lane, ai, af, ag, ao);
        const float* hh = dyn + 12288 + (wv*4)*512;
        dot4(g_hatt4 + rp*(512*64), 512, hh, hh+512, hh+1024, hh+1536, lane, ai, af, ag, ao);
        const float c = g_catt[jrow*64 + lane];
        const float cn = sigf(af)*c + sigf(ai)*tanhf_fast(ag);
        const float hn = sigf(ao)*tanhf_fast(cn);
        g_catt[jrow*64 + lane] = cn;
        g_hatt4[wp*(512*64) + bb*256 + lane*4 + wv] = hn;
        g_hattT[lane*512 + jrow] = hn;
      }
    } else {
      if (t > 0) {
        float ai = bi, af = bfg, ag = bgg, ao = bog;
        const float* w0 = dyn + (wv*4 + 0)*1024;
        const float* w1 = dyn + (wv*4 + 1)*1024;
        const float* w2 = dyn + (wv*4 + 2)*1024;
        const float* w3 = dyn + (wv*4 + 3)*1024;
        dot4(g_hatt4 + rp*(512*64), 512, w0, w1, w2, w3, lane, ai, af, ag, ao);
        dot4(g_ctx4, 512, w0+512, w1+512, w2+512, w3+512, lane, ai, af, ag, ao);
        const float* hh = dyn + 16384 + (wv*4)*512;
        dot4(g_hdec4 + wp*(512*64), 512, hh, hh+512, hh+1024, hh+1536, lane, ai, af, ag, ao);
        const float c = g_cdec[jrow*64 + lane];
        const float cn = sigf(af)*c + sigf(ai)*tanhf_fast(ag);
        const float hn = sigf(ao)*tanhf_fast(cn);
        g_cdec[jrow*64 + lane] = cn;
        g_hdec4[rp*(512*64) + (bb-128)*256 + lane*4 + wv] = hn;
      }
    }
    gbar(++bn, bb, tid);

    // ---- P3: energies (q inline) | mel/stop(t-1) | pre1(t+1) ----
    if (t < 500) {
      for (int i = tid; i < 512; i += 256) s_h[i] = g_hattT[eb*512 + i];
      for (int i = tid; i < 300; i += 256) {
        s_aa[15 + i] = g_a[eb*300 + i];
        s_aa[347 + i] = g_acum[eb*300 + i];
      }
      __syncthreads();
      float q1 = qb2.x, q2 = qb2.y;
#pragma unroll 8
      for (int k = 0; k < 512; k += 2) {
        const float h0 = s_h[k], h1 = s_h[k+1];
        const float2 wA = *(const float2*)(g_qwt + (size_t)k*512 + da);
        const float2 wB = *(const float2*)(g_qwt + (size_t)(k+1)*512 + da);
        q1 = fmaf(wA.x, h0, q1); q2 = fmaf(wA.y, h0, q2);
        q1 = fmaf(wB.x, h1, q1); q2 = fmaf(wB.y, h1, q2);
      }
      for (int i = tid; i < 75*32; i += 256) {   // conv into sbuf [75 tt][32 c], branch-free
        const int ttl = i >> 5, c2 = i & 31;
        const int tt = tt0 + ttl;
        float s = s_cw[1984 + c2];
#pragma unroll
        for (int k = 0; k < 31; ++k) {
          s = fmaf(s_cw[c2*62 + k],      s_aa[tt + k], s);
          s = fmaf(s_cw[c2*62 + 31 + k], s_aa[332 + tt + k], s);
        }
        sbuf[i] = s;
      }
      __syncthreads();
#pragma unroll
      for (int i = 0; i < 75; ++i) {
        float s1 = q1 + us2f((unsigned short)(mpq[i] & 0xffffu));
        float s2 = q2 + us2f((unsigned short)(mpq[i] >> 16));
#pragma unroll
        for (int c = 0; c < 32; ++c) {
          const float cv = sbuf[i*32 + c];
          s1 = fmaf(Pa[c], cv, s1);
          s2 = fmaf(Pb[c], cv, s2);
        }
        float p = v1*tanhf_fast(s1) + v2*tanhf_fast(s2);
#pragma unroll
        for (int m = 32; m >= 1; m >>= 1) p += __shfl_xor(p, m, 64);
        if (lane == 0) part[wv][i] = p;
      }
      __syncthreads();
      if (tid < 75)
        g_e[eb*300 + tt0 + tid] =
            part[0][tid] + part[1][tid] + part[2][tid] + part[3][tid] + vb;
    }
    if (t > 0 && bb < 20) {          // mel(t-1)
      const float* HD = g_hdec4 + rp*(512*64) + lane*4;
      float acc = prb;
      const float* wr = s_sm + wv*512;
#pragma unroll 4
      for (int k = 0; k < 512; k += 4) {
        float4 u = *(const float4*)(wr + k);
        float4 x = *(const float4*)(HD + k*64);
        acc = fmaf(u.x,x.x,acc); acc = fmaf(u.y,x.y,acc);
        acc = fmaf(u.z,x.z,acc); acc = fmaf(u.w,x.w,acc);
      }
      const int m = bb*4 + wv;
      const size_t oidx = (size_t)(lane*500 + (t-1))*80 + m;
      if (f32io) outf[oidx] = acc; else outh[oidx] = __float2bfloat16(acc);
    } else if (t > 0 && bb == 20 && tid < 64) {   // stop(t-1)
      const float* HD = g_hdec4 + rp*(512*64) + tid*4;
      float acc = g_scal[1];
#pragma unroll 4
      for (int k = 0; k < 512; k += 4) {
        float4 u = *(const float4*)(s_sm + k);
        float4 x = *(const float4*)(HD + k*64);
        acc = fmaf(u.x,x.x,acc); acc = fmaf(u.y,x.y,acc);
        acc = fmaf(u.z,x.z,acc); acc = fmaf(u.w,x.w,acc);
      }
      const size_t oidx = 2560000 + tid*500 + (t-1);
      if (f32io) outf[oidx] = acc; else outh[oidx] = __float2bfloat16(acc);
    }
    if (t <= 498 && bb >= 192) {     // pre1(t+1)
      float acc = prb;
      const float* mt = g_melT + (size_t)(t+1)*5120 + lane;
      const float* wr = s_sm + wv*80;
#pragma unroll 8
      for (int m = 0; m < 80; ++m) acc = fmaf(wr[m], mt[m*64], acc);
      g_pm1t4[(bb-192)*256 + lane*4 + wv] = fmaxf(acc, 0.f);
    }
    gbar(++bn, bb, tid);

    // ---- P4: softmax + a/a_cum + ctx(t) [0..63] | pre2(t+1) [64..127] ----
    if (t < 500) {
      if (bb < 64) {
        float* pl = sbuf; float* red = sbuf + 304;
        const int b_ = bb;
        const float* Ep = g_e + b_*300;
        float e1 = Ep[tid];
        float e2 = (tid + 256 < 300) ? Ep[tid + 256] : -3e38f;
        red[tid] = fmaxf(e1, e2); __syncthreads();
        for (int s = 128; s > 0; s >>= 1) { if (tid < s) red[tid] = fmaxf(red[tid], red[tid+s]); __syncthreads(); }
        const float mx = red[0]; __syncthreads();
        float p1 = __expf(e1 - mx);
        float p2 = (tid + 256 < 300) ? __expf(e2 - mx) : 0.f;
        pl[tid] = p1;
        if (tid + 256 < 300) pl[tid + 256] = p2;
        red[tid] = p1 + p2; __syncthreads();
        for (int s = 128; s > 0; s >>= 1) { if (tid < s) red[tid] += red[tid+s]; __syncthreads(); }
        const float inv = 1.f / red[0];
        const float av = pl[tid]*inv;
        g_a[b_*300 + tid] = av; g_acum[b_*300 + tid] += av;
        if (tid + 256 < 300) {
          const float av2 = pl[tid+256]*inv;
          g_a[b_*300 + tid+256] = av2; g_acum[b_*300 + tid+256] += av2;
        }
        __syncthreads();
        const float* ep = g_enc + (size_t)(b_*300)*512;
#pragma unroll
        for (int h = 0; h < 2; ++h) {
          const int dd = tid + h*256;
          float acc = 0.f;
#pragma unroll 4
          for (int tt = 0; tt < 300; ++tt) acc = fmaf(pl[tt], ep[(size_t)tt*512 + dd], acc);
          g_ctx4[(dd >> 2)*256 + b_*4 + (dd & 3)] = acc * inv;
        }
      } else if (bb < 128) {
        if (t <= 498) {   // pre2(t+1)
          float acc = prb;
          const float* wr = s_sm + wv*256;
          const float* xp = g_pm1t4 + lane*4;
#pragma unroll 4
          for (int k = 0; k < 256; k += 4) {
            float4 u = *(const float4*)(wr + k);
            float4 x = *(const float4*)(xp + k*64);
            acc = fmaf(u.x,x.x,acc); acc = fmaf(u.y,x.y,acc);
            acc = fmaf(u.z,x.z,acc); acc = fmaf(u.w,x.w,acc);
          }
          g_pmt4[(bb-64)*256 + lane*4 + wv] = fmaxf(acc, 0.f);
        }
      }
    }
    gbar(++bn, bb, tid);
  }
}

// ---------------- host ----------------
extern "C" void kernel_launch(void* const* d_in, const int* in_sizes, int n_in,
                              void* d_out, int out_size, void* d_ws, size_t ws_size,
                              hipStream_t stream) {
  (void)d_ws; (void)ws_size; (void)in_sizes; (void)out_size;
  static int s_attr = 0;
  if (!s_attr) {
    hipFuncSetAttribute((const void*)k_dec, hipFuncAttributeMaxDynamicSharedMemorySize, DYN_BYTES);
    s_attr = 1;
  }
  InPtrs P;
  for (int i = 0; i < 28 && i < n_in; ++i) P.p[i] = d_in[i];
  k_convert<<<dim3(2048), dim3(256), 0, stream>>>(P);
  k_dec<<<dim3(NB), dim3(256), DYN_BYTES, stream>>>(d_out);
}

// Round 2
// 168936.841 us; speedup vs baseline: 1.6873x; 1.2606x over previous
//
#include <hip/hip_runtime.h>
#include <hip/hip_bf16.h>

// Decoder_62079457296567 — Tacotron2-style decoder, B=64 T_enc=300 T_dec=500 D=512 MEL=80 PRE=256
// Round 9: fence-free grid barrier + LLC-coherent state atomics.
//  - ALL cross-block state via __hip_atomic_{load,store}(RELAXED, AGENT) (sc1, coherent at LLC).
//  - gbar: vmcnt-drain + flag relay only — NO __threadfence → L2 never invalidated →
//    read-only data (qwt 1MB/block/step, enc, melT, LDS-missed weights) stays L2-hot.
//  - P1 LSTM dots k-split across waves (each wave: k-quarter × all 16 gate rows, LDS reduce)
//    → 4x fewer LLC-latency state loads per block.
//  - mel/stop moved P3→P4 (blocks 128..148, otherwise idle); P3 = energies (+pre1) only.
// 256 blocks x 256 threads, ~134KB LDS -> 1 block/CU, co-resident.

#define DEV __device__ __forceinline__
typedef __hip_bfloat16 bf16;
DEV float b2f(bf16 x) { return __bfloat162float(x); }
DEV unsigned short f2us(float f) { bf16 h = __float2bfloat16(f); unsigned short u; __builtin_memcpy(&u, &h, 2); return u; }
DEV float us2f(unsigned short u) { union { float f; unsigned int i; } c; c.i = ((unsigned)u) << 16; return c.f; }

constexpr int NB = 256;
constexpr int DYN_BYTES = 98304;   // dec blocks: 16*1024 + 16*512 floats = 96 KB

// ---------------- canonical fp32 inputs (device .bss) ----------------
__device__ float g_enc[64*300*512];
__device__ __align__(16) float g_melT[500*80*64];   // [t][m][b]
__device__ float g_w1[256*80];
__device__ float g_b1[256];
__device__ float g_w2[256*256];
__device__ float g_b2[256];
__device__ float g_awih[2048*768];
__device__ float g_awhh[2048*512];
__device__ float g_ab[2048];
__device__ float g_dwih[2048*1024];
__device__ float g_dwhh[2048*512];
__device__ float g_db[2048];
__device__ float g_qwt[512*512];     // q_w^T [k][d]
__device__ float g_qpb[512];
__device__ float g_memwt[512*512];   // mem_w^T [k][d]
__device__ float g_memb[512];
__device__ float g_cw[32*62];
__device__ float g_cb[32];
__device__ float g_pw[512*32];
__device__ float g_vw[512];
__device__ float g_melw[80*512];
__device__ float g_melb[80];
__device__ float g_stopw[512];
__device__ float g_scal[2];          // v_b, stop_b
__device__ int   g_f32io;
// ---------------- recurrent state (X4 layout: [k>>2][b][k&3]) — ATOMIC ACCESS ONLY ----------------
__device__ __align__(16) float g_hatt4[2*512*64];
__device__ __align__(16) float g_hattT[64*512];     // [b][k] for q staging
__device__ float g_catt[512*64];                    // block-private (plain)
__device__ __align__(16) float g_hdec4[2*512*64];
__device__ float g_cdec[512*64];                    // block-private (plain)
__device__ __align__(16) float g_ctx4[512*64];
__device__ float g_a[64*300];
__device__ float g_acum[64*300];
__device__ __align__(16) float g_pmt4[256*64];
__device__ __align__(16) float g_pm1t4[256*64];
__device__ float g_e[64*300];
// ---------------- barrier (flag relay; zeroed by k_convert each launch) ----------------
__device__ int g_flag[NB*32];
__device__ int g_go[16*32];

struct InPtrs { const void* p[28]; };

DEV float sigf(float x) { return 1.f / (1.f + __expf(-x)); }
DEV float tanhf_fast(float x) {
  float e = __expf(-2.f * fabsf(x));
  float r = (1.f - e) / (1.f + e);
  return copysignf(r, x);
}

// ---- LLC-coherent (agent-scope relaxed) state accessors ----
DEV float ald(const float* p) {
  return __hip_atomic_load(p, __ATOMIC_RELAXED, __HIP_MEMORY_SCOPE_AGENT);
}
DEV void ast(float* p, float v) {
  __hip_atomic_store(p, v, __ATOMIC_RELAXED, __HIP_MEMORY_SCOPE_AGENT);
}
DEV float2 ald2(const float* p) {
  unsigned long long u = __hip_atomic_load((const unsigned long long*)p,
                                           __ATOMIC_RELAXED, __HIP_MEMORY_SCOPE_AGENT);
  union { unsigned long long u; float2 f; } c; c.u = u; return c.f;
}

DEV int detect_f32(const void* enc_raw) {
  const unsigned short* u = (const unsigned short*)enc_raw;
  int big = 0;
  for (int i = 0; i < 256; i += 2) { int e = (u[i] >> 7) & 0xFF; big += (e > 133) ? 1 : 0; }
  return big >= 8 ? 1 : 0;
}
DEV float ldin(const void* p, int i, int f32) {
  return f32 ? ((const float*)p)[i] : b2f(((const bf16*)p)[i]);
}

// ---------------- conversion kernel (also zeroes state + barrier) ----------------
__global__ __launch_bounds__(256) void k_convert(InPtrs P) {
  const int NT = gridDim.x * 256;
  const int flat = blockIdx.x * 256 + threadIdx.x;
  const int f32 = detect_f32(P.p[0]);
  if (flat == 0) {
    g_f32io = f32;
    g_scal[0] = ldin(P.p[23], 0, f32);
    g_scal[1] = ldin(P.p[27], 0, f32);
  }
#define CVT(dst, idx, n) for (int i = flat; i < (n); i += NT) dst[i] = ldin(P.p[idx], i, f32);
  CVT(g_enc, 0, 64*300*512)
  CVT(g_w1, 2, 256*80)   CVT(g_b1, 3, 256)
  CVT(g_w2, 4, 256*256)  CVT(g_b2, 5, 256)
  CVT(g_awih, 6, 2048*768)  CVT(g_awhh, 7, 2048*512)
  CVT(g_dwih, 10, 2048*1024) CVT(g_dwhh, 11, 2048*512)
  CVT(g_cw, 18, 32*62) CVT(g_cb, 19, 32)
  CVT(g_pw, 20, 512*32)  CVT(g_vw, 22, 512)
  CVT(g_melw, 24, 80*512) CVT(g_melb, 25, 80)
  CVT(g_stopw, 26, 512)  CVT(g_memb, 17, 512)
#undef CVT
  // mel transpose: g_melT[(t*80+m)*64 + b] = mel[b][t][m]
  for (int i = flat; i < 500*80*64; i += NT) {
    int b = i & 63, tm = i >> 6;
    g_melT[i] = ldin(P.p[1], b*40000 + tm, f32);
  }
  for (int i = flat; i < 2048; i += NT) g_ab[i] = ldin(P.p[8], i, f32) + ldin(P.p[9], i, f32);
  for (int i = flat; i < 2048; i += NT) g_db[i] = ldin(P.p[12], i, f32) + ldin(P.p[13], i, f32);
  for (int i = flat; i < 512; i += NT) g_qpb[i] = ldin(P.p[15], i, f32) + ldin(P.p[21], i, f32);
  for (int o = flat; o < 512*512; o += NT) {
    int d = o >> 9, k = o & 511;
    g_memwt[(size_t)k*512 + d] = ldin(P.p[16], o, f32);
    g_qwt[(size_t)k*512 + d]   = ldin(P.p[14], o, f32);
  }
  // zero state + barrier (plain stores: kernel-end flush makes them LLC-visible)
  for (int i = flat; i < 2*512*64; i += NT) { g_hatt4[i] = 0.f; g_hdec4[i] = 0.f; }
  for (int i = flat; i < 512*64; i += NT) { g_catt[i] = 0.f; g_cdec[i] = 0.f; g_ctx4[i] = 0.f; }
  for (int i = flat; i < 64*512; i += NT) g_hattT[i] = 0.f;
  for (int i = flat; i < 64*300; i += NT) { g_a[i] = 0.f; g_acum[i] = 0.f; }
  for (int i = flat; i < NB*32; i += NT) g_flag[i] = 0;
  for (int i = flat; i < 16*32; i += NT) g_go[i] = 0;
}

// ---------------- fence-free flag/relay grid barrier ----------------
// All cross-block data moves via agent-scope sc1 atomics (coherent at LLC), so the
// barrier only needs: drain own vmcnt -> flag -> relay. No L2 writeback/invalidate.
DEV void gbar(int n, int bb, int tid) {
  asm volatile("s_waitcnt vmcnt(0) lgkmcnt(0)" ::: "memory");
  __syncthreads();
  if (tid == 0)
    __hip_atomic_store(&g_flag[bb*32], n, __ATOMIC_RELAXED, __HIP_MEMORY_SCOPE_AGENT);
  if (bb == 0) {
    while (__hip_atomic_load(&g_flag[tid*32], __ATOMIC_RELAXED, __HIP_MEMORY_SCOPE_AGENT) < n)
      __builtin_amdgcn_s_sleep(1);
    __syncthreads();
    if (tid < 16)
      __hip_atomic_store(&g_go[tid*32], n, __ATOMIC_RELAXED, __HIP_MEMORY_SCOPE_AGENT);
  } else {
    if (tid == 0) {
      while (__hip_atomic_load(&g_go[(bb>>4)*32], __ATOMIC_RELAXED, __HIP_MEMORY_SCOPE_AGENT) < n)
        __builtin_amdgcn_s_sleep(1);
    }
  }
  __syncthreads();
}

// k-split 16-row dot: this wave covers k in [k0,k0+nk) for ALL 16 gate-rows of the block.
// Weights from LDS (row r at W + r*STRIDE), X from LLC-coherent state ([k>>2][b][k&3]).
template<int STRIDE>
DEV void dot16(const float* __restrict__ X4, const float* __restrict__ W,
               int k0, int nk, int lane, float* acc) {
#pragma unroll 2
  for (int k = k0; k < k0 + nk; k += 8) {
    const float* xp = X4 + k*64 + lane*4;
    float2 xa0 = ald2(xp);
    float2 xb0 = ald2(xp + 2);
    float2 xa1 = ald2(xp + 256);
    float2 xb1 = ald2(xp + 258);
#pragma unroll
    for (int r = 0; r < 16; ++r) {
      const float* wp = W + r*STRIDE + k;
      float4 w0 = *(const float4*)(wp);
      float4 w1 = *(const float4*)(wp + 4);
      acc[r] = fmaf(w0.x, xa0.x, acc[r]); acc[r] = fmaf(w0.y, xa0.y, acc[r]);
      acc[r] = fmaf(w0.z, xb0.x, acc[r]); acc[r] = fmaf(w0.w, xb0.y, acc[r]);
      acc[r] = fmaf(w1.x, xa1.x, acc[r]); acc[r] = fmaf(w1.y, xa1.y, acc[r]);
      acc[r] = fmaf(w1.z, xb1.x, acc[r]); acc[r] = fmaf(w1.w, xb1.y, acc[r]);
    }
  }
}

// single-row dot: LDS weights, LLC-coherent X. One output per thread (row, col=lane).
DEV float dotS(const float* __restrict__ X4, const float* __restrict__ wr,
               int n, int lane, float acc) {
#pragma unroll 2
  for (int k = 0; k < n; k += 8) {
    const float* xp = X4 + k*64 + lane*4;
    float2 xa0 = ald2(xp);
    float2 xb0 = ald2(xp + 2);
    float2 xa1 = ald2(xp + 256);
    float2 xb1 = ald2(xp + 258);
    float4 u0 = *(const float4*)(wr + k);
    float4 u1 = *(const float4*)(wr + k + 4);
    acc = fmaf(u0.x, xa0.x, acc); acc = fmaf(u0.y, xa0.y, acc);
    acc = fmaf(u0.z, xb0.x, acc); acc = fmaf(u0.w, xb0.y, acc);
    acc = fmaf(u1.x, xa1.x, acc); acc = fmaf(u1.y, xa1.y, acc);
    acc = fmaf(u1.z, xb1.x, acc); acc = fmaf(u1.w, xb1.y, acc);
  }
  return acc;
}

__global__ __launch_bounds__(256) void k_dec(void* outv) {
  const int bb = blockIdx.x;
  const int tid = threadIdx.x;
  const int lane = tid & 63, wv = tid >> 6;
  const int f32io = g_f32io;
  bf16* outh = (bf16*)outv;
  float* outf = (float*)outv;

  extern __shared__ float dyn[];                 // persistent LSTM weights
  __shared__ float sbuf[4096];                   // P1: part16 [16][4][64]; P3: conv; P4: softmax
  __shared__ float part[4][76];
  __shared__ float s_h[512];                     // h_att[eb] for q-dot
  __shared__ float s_aa[664];                    // padded a [0..330) / acum [332..662)
  __shared__ float s_cw[2016];                   // conv weights + bias @1984
  __shared__ __align__(16) float s_sm[2048];     // role weights: melw/stopw/w2/w1 rows

  const int eb = bb >> 2, tt0 = (bb & 3) * 75;
  const int da = wv*128 + lane*2;                // d-pair (da, da+1)
  int bn = 0;

  // ---- one-time LDS persist ----
  if (bb < 128) {
    for (int r = 0; r < 16; ++r) {
      const int grow = (r & 3)*512 + bb*4 + (r >> 2);       // gate*512 + unit
      for (int c = tid; c < 768; c += 256) dyn[r*768 + c] = g_awih[(size_t)grow*768 + c];
      for (int c = tid; c < 512; c += 256) dyn[12288 + r*512 + c] = g_awhh[(size_t)grow*512 + c];
    }
  } else {
    for (int r = 0; r < 16; ++r) {
      const int grow = (r & 3)*512 + (bb - 128)*4 + (r >> 2);
      for (int c = tid; c < 1024; c += 256) dyn[r*1024 + c] = g_dwih[(size_t)grow*1024 + c];
      for (int c = tid; c < 512; c += 256) dyn[16384 + r*512 + c] = g_dwhh[(size_t)grow*512 + c];
    }
  }
  for (int i = tid; i < 1984; i += 256) s_cw[i] = g_cw[i];
  for (int i = tid; i < 32; i += 256) s_cw[1984 + i] = g_cb[i];
  if (bb >= 128 && bb < 148)        { for (int i = tid; i < 2048; i += 256) s_sm[i] = g_melw[(bb-128)*2048 + i]; }
  else if (bb == 148)               { for (int i = tid; i < 512;  i += 256) s_sm[i] = g_stopw[i]; }
  else if (bb >= 64 && bb < 128)    { for (int i = tid; i < 1024; i += 256) s_sm[i] = g_w2[(bb-64)*1024 + i]; }
  else if (bb >= 192)               { for (int i = tid; i < 320;  i += 256) s_sm[i] = g_w1[(bb-192)*320 + i]; }
  for (int i = tid; i < 664; i += 256) s_aa[i] = 0.f;      // zero pads once
  __syncthreads();

  // per-wave / per-role register preloads
  const int jrow = __builtin_amdgcn_readfirstlane((bb < 128 ? bb*4 : (bb-128)*4) + wv);
  float bi, bfg, bgg, bog;
  if (bb < 128) { bi = g_ab[jrow]; bfg = g_ab[512+jrow]; bgg = g_ab[1024+jrow]; bog = g_ab[1536+jrow]; }
  else          { bi = g_db[jrow]; bfg = g_db[512+jrow]; bgg = g_db[1024+jrow]; bog = g_db[1536+jrow]; }
  float prb = 0.f;
  if (bb >= 128 && bb < 148) prb = g_melb[(bb-128)*4 + wv];
  else if (bb >= 64 && bb < 128) prb = g_b2[(bb-64)*4 + wv];
  else if (bb >= 192) prb = g_b1[(bb-192)*4 + wv];

  // ---- Pr0: pre1(0) on blocks 192..255 ----
  if (bb >= 192) {
    float acc = prb;
    const float* mt = g_melT + lane;             // t=0
    const float* wr = s_sm + wv*80;
#pragma unroll 8
    for (int m = 0; m < 80; ++m) acc = fmaf(wr[m], mt[m*64], acc);
    ast(&g_pm1t4[(bb-192)*256 + lane*4 + wv], fmaxf(acc, 0.f));
  }
  gbar(++bn, bb, tid);

  // ---- Pr1: mproj chunk -> registers (packed bf16x2); pre2(0) on blocks 64..127 ----
  unsigned int mpq[75];
  {
    float a1[75], a2[75];
#pragma unroll
    for (int r = 0; r < 75; ++r) { a1[r] = 0.f; a2[r] = 0.f; }
    for (int kt = 0; kt < 16; ++kt) {
      __syncthreads();
      for (int i = tid; i < 75*32; i += 256) {
        int r = i >> 5, kk = i & 31;
        sbuf[i] = g_enc[((size_t)eb*300 + tt0 + r)*512 + kt*32 + kk];
      }
      __syncthreads();
      for (int kk = 0; kk < 32; ++kk) {
        const int k = kt*32 + kk;
        const float2 w = *(const float2*)(g_memwt + (size_t)k*512 + da);
#pragma unroll
        for (int r = 0; r < 75; ++r) {
          const float ev = sbuf[r*32 + kk];
          a1[r] = fmaf(ev, w.x, a1[r]);
          a2[r] = fmaf(ev, w.y, a2[r]);
        }
      }
    }
    const float2 mb = *(const float2*)(g_memb + da);
#pragma unroll
    for (int r = 0; r < 75; ++r)
      mpq[r] = (unsigned)f2us(a1[r] + mb.x) | ((unsigned)f2us(a2[r] + mb.y) << 16);
    if (bb >= 64 && bb < 128) {      // pre2(0)
      float acc = dotS(g_pm1t4, s_sm + wv*256, 256, lane, prb);
      ast(&g_pmt4[(bb-64)*256 + lane*4 + wv], fmaxf(acc, 0.f));
    }
  }
  float Pa[32], Pb[32];
#pragma unroll
  for (int i = 0; i < 8; ++i) {
    float4 u = *(const float4*)(g_pw + (size_t)da*32 + 4*i);
    float4 w = *(const float4*)(g_pw + (size_t)(da+1)*32 + 4*i);
    Pa[4*i] = u.x; Pa[4*i+1] = u.y; Pa[4*i+2] = u.z; Pa[4*i+3] = u.w;
    Pb[4*i] = w.x; Pb[4*i+1] = w.y; Pb[4*i+2] = w.z; Pb[4*i+3] = w.w;
  }
  const float2 vv  = *(const float2*)(g_vw + da);
  const float2 qb2 = *(const float2*)(g_qpb + da);
  const float v1 = vv.x, v2 = vv.y;
  const float vb = g_scal[0];
  gbar(++bn, bb, tid);

  // ================= main loop: 3 barriers/step =================
  for (int t = 0; t <= 500; ++t) {
    const int rp = t & 1, wp = rp ^ 1;

    // ---- P1: att-LSTM(t) [0..127] | dec-LSTM(t-1) [128..255], k-split across waves ----
    if (bb < 128) {
      if (t < 500) {
        float acc[16];
#pragma unroll
        for (int r = 0; r < 16; ++r) acc[r] = 0.f;
        dot16<768>(g_pmt4, dyn, wv*64, 64, lane, acc);
        dot16<768>(g_ctx4, dyn + 256, wv*128, 128, lane, acc);
        dot16<512>(g_hatt4 + rp*(512*64), dyn + 12288, wv*128, 128, lane, acc);
#pragma unroll
        for (int r = 0; r < 16; ++r) sbuf[r*256 + wv*64 + lane] = acc[r];
        __syncthreads();
        float s0 = 0.f, s1 = 0.f, s2 = 0.f, s3 = 0.f;
#pragma unroll
        for (int w = 0; w < 4; ++w) {
          s0 += sbuf[(wv*4+0)*256 + w*64 + lane];
          s1 += sbuf[(wv*4+1)*256 + w*64 + lane];
          s2 += sbuf[(wv*4+2)*256 + w*64 + lane];
          s3 += sbuf[(wv*4+3)*256 + w*64 + lane];
        }
        const float ai = bi + s0, af = bfg + s1, ag = bgg + s2, ao = bog + s3;
        const float c = g_catt[jrow*64 + lane];
        const float cn = sigf(af)*c + sigf(ai)*tanhf_fast(ag);
        const float hn = sigf(ao)*tanhf_fast(cn);
        g_catt[jrow*64 + lane] = cn;
        ast(&g_hatt4[wp*(512*64) + bb*256 + lane*4 + wv], hn);
        ast(&g_hattT[lane*512 + jrow], hn);
      }
    } else {
      if (t > 0) {
        float acc[16];
#pragma unroll
        for (int r = 0; r < 16; ++r) acc[r] = 0.f;
        dot16<1024>(g_hatt4 + rp*(512*64), dyn, wv*128, 128, lane, acc);
        dot16<1024>(g_ctx4, dyn + 512, wv*128, 128, lane, acc);
        dot16<512>(g_hdec4 + wp*(512*64), dyn + 16384, wv*128, 128, lane, acc);
#pragma unroll
        for (int r = 0; r < 16; ++r) sbuf[r*256 + wv*64 + lane] = acc[r];
        __syncthreads();
        float s0 = 0.f, s1 = 0.f, s2 = 0.f, s3 = 0.f;
#pragma unroll
        for (int w = 0; w < 4; ++w) {
          s0 += sbuf[(wv*4+0)*256 + w*64 + lane];
          s1 += sbuf[(wv*4+1)*256 + w*64 + lane];
          s2 += sbuf[(wv*4+2)*256 + w*64 + lane];
          s3 += sbuf[(wv*4+3)*256 + w*64 + lane];
        }
        const float ai = bi + s0, af = bfg + s1, ag = bgg + s2, ao = bog + s3;
        const float c = g_cdec[jrow*64 + lane];
        const float cn = sigf(af)*c + sigf(ai)*tanhf_fast(ag);
        const float hn = sigf(ao)*tanhf_fast(cn);
        g_cdec[jrow*64 + lane] = cn;
        ast(&g_hdec4[rp*(512*64) + (bb-128)*256 + lane*4 + wv], hn);
      }
    }
    gbar(++bn, bb, tid);

    // ---- P3: energies (q inline, all blocks) | pre1(t+1) [192..255] ----
    if (t < 500) {
      for (int i = tid; i < 512; i += 256) s_h[i] = ald(&g_hattT[eb*512 + i]);
      for (int i = tid; i < 300; i += 256) {
        s_aa[15 + i] = ald(&g_a[eb*300 + i]);
        s_aa[347 + i] = ald(&g_acum[eb*300 + i]);
      }
      __syncthreads();
      float q1 = qb2.x, q2 = qb2.y;
#pragma unroll 8
      for (int k = 0; k < 512; k += 2) {
        const float h0 = s_h[k], h1 = s_h[k+1];
        const float2 wA = *(const float2*)(g_qwt + (size_t)k*512 + da);
        const float2 wB = *(const float2*)(g_qwt + (size_t)(k+1)*512 + da);
        q1 = fmaf(wA.x, h0, q1); q2 = fmaf(wA.y, h0, q2);
        q1 = fmaf(wB.x, h1, q1); q2 = fmaf(wB.y, h1, q2);
      }
      for (int i = tid; i < 75*32; i += 256) {   // conv into sbuf [75 tt][32 c], branch-free
        const int ttl = i >> 5, c2 = i & 31;
        const int tt = tt0 + ttl;
        float s = s_cw[1984 + c2];
#pragma unroll
        for (int k = 0; k < 31; ++k) {
          s = fmaf(s_cw[c2*62 + k],      s_aa[tt + k], s);
          s = fmaf(s_cw[c2*62 + 31 + k], s_aa[332 + tt + k], s);
        }
        sbuf[i] = s;
      }
      __syncthreads();
#pragma unroll
      for (int i = 0; i < 75; ++i) {
        float s1 = q1 + us2f((unsigned short)(mpq[i] & 0xffffu));
        float s2 = q2 + us2f((unsigned short)(mpq[i] >> 16));
#pragma unroll
        for (int c = 0; c < 32; ++c) {
          const float cv = sbuf[i*32 + c];
          s1 = fmaf(Pa[c], cv, s1);
          s2 = fmaf(Pb[c], cv, s2);
        }
        float p = v1*tanhf_fast(s1) + v2*tanhf_fast(s2);
#pragma unroll
        for (int m = 32; m >= 1; m >>= 1) p += __shfl_xor(p, m, 64);
        if (lane == 0) part[wv][i] = p;
      }
      __syncthreads();
      if (tid < 75)
        ast(&g_e[eb*300 + tt0 + tid],
            part[0][tid] + part[1][tid] + part[2][tid] + part[3][tid] + vb);
    }
    if (t <= 498 && bb >= 192) {     // pre1(t+1)
      float acc = prb;
      const float* mt = g_melT + (size_t)(t+1)*5120 + lane;
      const float* wr = s_sm + wv*80;
#pragma unroll 8
      for (int m = 0; m < 80; ++m) acc = fmaf(wr[m], mt[m*64], acc);
      ast(&g_pm1t4[(bb-192)*256 + lane*4 + wv], fmaxf(acc, 0.f));
    }
    gbar(++bn, bb, tid);

    // ---- P4: softmax+ctx [0..63] | pre2(t+1) [64..127] | mel/stop(t-1) [128..148] ----
    if (t < 500) {
      if (bb < 64) {
        float* pl = sbuf; float* red = sbuf + 304;
        const int b_ = bb;
        const float* Ep = g_e + b_*300;
        float e1 = ald(Ep + tid);
        float e2 = (tid + 256 < 300) ? ald(Ep + tid + 256) : -3e38f;
        red[tid] = fmaxf(e1, e2); __syncthreads();
        for (int s = 128; s > 0; s >>= 1) { if (tid < s) red[tid] = fmaxf(red[tid], red[tid+s]); __syncthreads(); }
        const float mx = red[0]; __syncthreads();
        float p1 = __expf(e1 - mx);
        float p2 = (tid + 256 < 300) ? __expf(e2 - mx) : 0.f;
        pl[tid] = p1;
        if (tid + 256 < 300) pl[tid + 256] = p2;
        red[tid] = p1 + p2; __syncthreads();
        for (int s = 128; s > 0; s >>= 1) { if (tid < s) red[tid] += red[tid+s]; __syncthreads(); }
        const float inv = 1.f / red[0];
        const float av = pl[tid]*inv;
        {
          const float oc = ald(&g_acum[b_*300 + tid]);
          ast(&g_a[b_*300 + tid], av);
          ast(&g_acum[b_*300 + tid], oc + av);
        }
        if (tid + 256 < 300) {
          const float av2 = pl[tid+256]*inv;
          const float oc2 = ald(&g_acum[b_*300 + tid+256]);
          ast(&g_a[b_*300 + tid+256], av2);
          ast(&g_acum[b_*300 + tid+256], oc2 + av2);
        }
        __syncthreads();
        const float* ep = g_enc + (size_t)(b_*300)*512;
#pragma unroll
        for (int h = 0; h < 2; ++h) {
          const int dd = tid + h*256;
          float acc = 0.f;
#pragma unroll 4
          for (int tt = 0; tt < 300; ++tt) acc = fmaf(pl[tt], ep[(size_t)tt*512 + dd], acc);
          ast(&g_ctx4[(dd >> 2)*256 + b_*4 + (dd & 3)], acc * inv);
        }
      } else if (bb < 128) {
        if (t <= 498) {   // pre2(t+1)
          float acc = dotS(g_pm1t4, s_sm + wv*256, 256, lane, prb);
          ast(&g_pmt4[(bb-64)*256 + lane*4 + wv], fmaxf(acc, 0.f));
        }
      }
    }
    if (t > 0 && bb >= 128 && bb < 148) {         // mel(t-1)
      float acc = dotS(g_hdec4 + rp*(512*64), s_sm + wv*512, 512, lane, prb);
      const int m = (bb-128)*4 + wv;
      const size_t oidx = (size_t)(lane*500 + (t-1))*80 + m;
      if (f32io) outf[oidx] = acc; else outh[oidx] = __float2bfloat16(acc);
    } else if (t > 0 && bb == 148 && tid < 64) {  // stop(t-1)
      float acc = dotS(g_hdec4 + rp*(512*64), s_sm, 512, tid, g_scal[1]);
      const size_t oidx = 2560000 + tid*500 + (t-1);
      if (f32io) outf[oidx] = acc; else outh[oidx] = __float2bfloat16(acc);
    }
    gbar(++bn, bb, tid);
  }
}

// ---------------- host ----------------
extern "C" void kernel_launch(void* const* d_in, const int* in_sizes, int n_in,
                              void* d_out, int out_size, void* d_ws, size_t ws_size,
                              hipStream_t stream) {
  (void)d_ws; (void)ws_size; (void)in_sizes; (void)out_size;
  static int s_attr = 0;
  if (!s_attr) {
    hipFuncSetAttribute((const void*)k_dec, hipFuncAttributeMaxDynamicSharedMemorySize, DYN_BYTES);
    s_attr = 1;
  }
  InPtrs P;
  for (int i = 0; i < 28 && i < n_in; ++i) P.p[i] = d_in[i];
  k_convert<<<dim3(2048), dim3(256), 0, stream>>>(P);
  k_dec<<<dim3(NB), dim3(256), DYN_BYTES, stream>>>(d_out);
}

// Round 3
// 111006.897 us; speedup vs baseline: 2.5678x; 1.5219x over previous
//
#include <hip/hip_runtime.h>
#include <hip/hip_bf16.h>

// Decoder_62079457296567 — Tacotron2-style decoder, B=64 T_enc=300 T_dec=500 D=512 MEL=80 PRE=256
// Round 10: pipe rebalance + TLP.
//  - 512 threads/block (8 waves/CU, occupancy 2x).
//  - LSTM/role weights: LDS -> global VMEM broadcast (z-trick). L2-hot now that the barrier is
//    fence-free. Frees the LDS pipe (was ~30us/step of ds_read_b128) and 96KB of LDS.
//  - P1 k-split across 8 waves; 16-row partials reduced via LDS.
//  - P3: conv tile read as float4 uniform (4x fewer LDS instrs); q-dot k-split across wave-halves;
//    energy rows split 0..37 / 38..74 across wave-halves (mpq 75->38 VGPRs).
//  - Barrier structure unchanged: fence-free flag/relay, 3 barriers/step, sc1 state atomics.

#define DEV __device__ __forceinline__
typedef __hip_bfloat16 bf16;
DEV float b2f(bf16 x) { return __bfloat162float(x); }
DEV unsigned short f2us(float f) { bf16 h = __float2bfloat16(f); unsigned short u; __builtin_memcpy(&u, &h, 2); return u; }
DEV float us2f(unsigned short u) { union { float f; unsigned int i; } c; c.i = ((unsigned)u) << 16; return c.f; }

constexpr int NB = 256;

// ---------------- canonical fp32 inputs (device .bss) ----------------
__device__ float g_enc[64*300*512];
__device__ __align__(16) float g_melT[500*80*64];   // [t][m][b]
__device__ __align__(16) float g_w1[256*80];
__device__ float g_b1[256];
__device__ __align__(16) float g_w2[256*256];
__device__ float g_b2[256];
__device__ __align__(16) float g_awih[2048*768];
__device__ __align__(16) float g_awhh[2048*512];
__device__ float g_ab[2048];
__device__ __align__(16) float g_dwih[2048*1024];
__device__ __align__(16) float g_dwhh[2048*512];
__device__ float g_db[2048];
__device__ __align__(16) float g_qwt[512*512];     // q_w^T [k][d]
__device__ float g_qpb[512];
__device__ __align__(16) float g_memwt[512*512];   // mem_w^T [k][d]
__device__ float g_memb[512];
__device__ float g_cw[32*62];
__device__ float g_cb[32];
__device__ __align__(16) float g_pw[512*32];
__device__ float g_vw[512];
__device__ __align__(16) float g_melw[80*512];
__device__ float g_melb[80];
__device__ __align__(16) float g_stopw[512];
__device__ float g_scal[2];          // v_b, stop_b
__device__ int   g_f32io;
// ---------------- recurrent state (X4 layout: [k>>2][b][k&3]) — sc1 atomics ----------------
__device__ __align__(16) float g_hatt4[2*512*64];
__device__ __align__(16) float g_hattT[64*512];     // [b][k] for q staging
__device__ float g_catt[512*64];                    // block-private (plain)
__device__ __align__(16) float g_hdec4[2*512*64];
__device__ float g_cdec[512*64];                    // block-private (plain)
__device__ __align__(16) float g_ctx4[512*64];
__device__ float g_a[64*300];
__device__ float g_acum[64*300];
__device__ __align__(16) float g_pmt4[256*64];
__device__ __align__(16) float g_pm1t4[256*64];
__device__ float g_e[64*300];
// ---------------- barrier (flag relay; zeroed by k_convert each launch) ----------------
__device__ int g_flag[NB*32];
__device__ int g_go[16*32];

struct InPtrs { const void* p[28]; };

DEV float sigf(float x) { return 1.f / (1.f + __expf(-x)); }
DEV float tanhf_fast(float x) {
  float e = __expf(-2.f * fabsf(x));
  float r = (1.f - e) / (1.f + e);
  return copysignf(r, x);
}
DEV int zero_vgpr() { int z; asm volatile("v_mov_b32 %0, 0" : "=v"(z)); return z; }

// ---- LLC-coherent (agent-scope relaxed) state accessors ----
DEV float ald(const float* p) {
  return __hip_atomic_load(p, __ATOMIC_RELAXED, __HIP_MEMORY_SCOPE_AGENT);
}
DEV void ast(float* p, float v) {
  __hip_atomic_store(p, v, __ATOMIC_RELAXED, __HIP_MEMORY_SCOPE_AGENT);
}
DEV float2 ald2(const float* p) {
  unsigned long long u = __hip_atomic_load((const unsigned long long*)p,
                                           __ATOMIC_RELAXED, __HIP_MEMORY_SCOPE_AGENT);
  union { unsigned long long u; float2 f; } c; c.u = u; return c.f;
}

DEV int detect_f32(const void* enc_raw) {
  const unsigned short* u = (const unsigned short*)enc_raw;
  int big = 0;
  for (int i = 0; i < 256; i += 2) { int e = (u[i] >> 7) & 0xFF; big += (e > 133) ? 1 : 0; }
  return big >= 8 ? 1 : 0;
}
DEV float ldin(const void* p, int i, int f32) {
  return f32 ? ((const float*)p)[i] : b2f(((const bf16*)p)[i]);
}

// ---------------- conversion kernel (also zeroes state + barrier) ----------------
__global__ __launch_bounds__(256) void k_convert(InPtrs P) {
  const int NT = gridDim.x * 256;
  const int flat = blockIdx.x * 256 + threadIdx.x;
  const int f32 = detect_f32(P.p[0]);
  if (flat == 0) {
    g_f32io = f32;
    g_scal[0] = ldin(P.p[23], 0, f32);
    g_scal[1] = ldin(P.p[27], 0, f32);
  }
#define CVT(dst, idx, n) for (int i = flat; i < (n); i += NT) dst[i] = ldin(P.p[idx], i, f32);
  CVT(g_enc, 0, 64*300*512)
  CVT(g_w1, 2, 256*80)   CVT(g_b1, 3, 256)
  CVT(g_w2, 4, 256*256)  CVT(g_b2, 5, 256)
  CVT(g_awih, 6, 2048*768)  CVT(g_awhh, 7, 2048*512)
  CVT(g_dwih, 10, 2048*1024) CVT(g_dwhh, 11, 2048*512)
  CVT(g_cw, 18, 32*62) CVT(g_cb, 19, 32)
  CVT(g_pw, 20, 512*32)  CVT(g_vw, 22, 512)
  CVT(g_melw, 24, 80*512) CVT(g_melb, 25, 80)
  CVT(g_stopw, 26, 512)  CVT(g_memb, 17, 512)
#undef CVT
  // mel transpose: g_melT[(t*80+m)*64 + b] = mel[b][t][m]
  for (int i = flat; i < 500*80*64; i += NT) {
    int b = i & 63, tm = i >> 6;
    g_melT[i] = ldin(P.p[1], b*40000 + tm, f32);
  }
  for (int i = flat; i < 2048; i += NT) g_ab[i] = ldin(P.p[8], i, f32) + ldin(P.p[9], i, f32);
  for (int i = flat; i < 2048; i += NT) g_db[i] = ldin(P.p[12], i, f32) + ldin(P.p[13], i, f32);
  for (int i = flat; i < 512; i += NT) g_qpb[i] = ldin(P.p[15], i, f32) + ldin(P.p[21], i, f32);
  for (int o = flat; o < 512*512; o += NT) {
    int d = o >> 9, k = o & 511;
    g_memwt[(size_t)k*512 + d] = ldin(P.p[16], o, f32);
    g_qwt[(size_t)k*512 + d]   = ldin(P.p[14], o, f32);
  }
  // zero state + barrier
  for (int i = flat; i < 2*512*64; i += NT) { g_hatt4[i] = 0.f; g_hdec4[i] = 0.f; }
  for (int i = flat; i < 512*64; i += NT) { g_catt[i] = 0.f; g_cdec[i] = 0.f; g_ctx4[i] = 0.f; }
  for (int i = flat; i < 64*512; i += NT) g_hattT[i] = 0.f;
  for (int i = flat; i < 64*300; i += NT) { g_a[i] = 0.f; g_acum[i] = 0.f; }
  for (int i = flat; i < NB*32; i += NT) g_flag[i] = 0;
  for (int i = flat; i < 16*32; i += NT) g_go[i] = 0;
}

// ---------------- fence-free flag/relay grid barrier (512-thread blocks) ----------------
DEV void gbar(int n, int bb, int tid) {
  asm volatile("s_waitcnt vmcnt(0) lgkmcnt(0)" ::: "memory");
  __syncthreads();
  if (tid == 0)
    __hip_atomic_store(&g_flag[bb*32], n, __ATOMIC_RELAXED, __HIP_MEMORY_SCOPE_AGENT);
  if (bb == 0) {
    if (tid < 256)
      while (__hip_atomic_load(&g_flag[tid*32], __ATOMIC_RELAXED, __HIP_MEMORY_SCOPE_AGENT) < n)
        __builtin_amdgcn_s_sleep(1);
    __syncthreads();
    if (tid < 16)
      __hip_atomic_store(&g_go[tid*32], n, __ATOMIC_RELAXED, __HIP_MEMORY_SCOPE_AGENT);
  } else {
    if (tid == 0) {
      while (__hip_atomic_load(&g_go[(bb>>4)*32], __ATOMIC_RELAXED, __HIP_MEMORY_SCOPE_AGENT) < n)
        __builtin_amdgcn_s_sleep(1);
    }
  }
  __syncthreads();
}

// k-split 16-row dot: this wave covers k in [k0,k0+nk) for ALL 16 gate-rows of the block.
// Weights from GLOBAL (VMEM broadcast, L2-hot), rows at (g*512 + bbu*4 + u)*RS.
// X from LLC-coherent state ([k>>2][b][k&3]).
template<int RS>
DEV void pdot16(const float* __restrict__ X4, const float* __restrict__ W0,
                int bbu, int k0, int nk, int lane, float* acc) {
#pragma unroll 2
  for (int k = k0; k < k0 + nk; k += 8) {
    const float* xp = X4 + k*64 + lane*4;
    float2 xa0 = ald2(xp);
    float2 xb0 = ald2(xp + 2);
    float2 xa1 = ald2(xp + 256);
    float2 xb1 = ald2(xp + 258);
#pragma unroll
    for (int g = 0; g < 4; ++g) {
#pragma unroll
      for (int u = 0; u < 4; ++u) {
        const float* wp = W0 + (size_t)(g*512 + bbu*4 + u)*RS + k;
        float4 w0 = *(const float4*)(wp);
        float4 w1 = *(const float4*)(wp + 4);
        float a = acc[g*4+u];
        a = fmaf(w0.x, xa0.x, a); a = fmaf(w0.y, xa0.y, a);
        a = fmaf(w0.z, xb0.x, a); a = fmaf(w0.w, xb0.y, a);
        a = fmaf(w1.x, xa1.x, a); a = fmaf(w1.y, xa1.y, a);
        a = fmaf(w1.z, xb1.x, a); a = fmaf(w1.w, xb1.y, a);
        acc[g*4+u] = a;
      }
    }
  }
}

// single-row dot: global weights (VMEM broadcast), LLC-coherent X. out = dot(w, X[:,lane]) + acc.
DEV float dotSg(const float* __restrict__ X4, const float* __restrict__ wr,
                int n, int lane, float acc) {
#pragma unroll 2
  for (int k = 0; k < n; k += 8) {
    const float* xp = X4 + k*64 + lane*4;
    float2 xa0 = ald2(xp);
    float2 xb0 = ald2(xp + 2);
    float2 xa1 = ald2(xp + 256);
    float2 xb1 = ald2(xp + 258);
    float4 u0 = *(const float4*)(wr + k);
    float4 u1 = *(const float4*)(wr + k + 4);
    acc = fmaf(u0.x, xa0.x, acc); acc = fmaf(u0.y, xa0.y, acc);
    acc = fmaf(u0.z, xb0.x, acc); acc = fmaf(u0.w, xb0.y, acc);
    acc = fmaf(u1.x, xa1.x, acc); acc = fmaf(u1.y, xa1.y, acc);
    acc = fmaf(u1.z, xb1.x, acc); acc = fmaf(u1.w, xb1.y, acc);
  }
  return acc;
}

__global__ __launch_bounds__(512) void k_dec(void* outv) {
  const int bb = blockIdx.x;
  const int tid = threadIdx.x;
  const int lane = tid & 63, wv = tid >> 6;        // wv 0..7
  const int h = wv >> 2, dwv = wv & 3;             // wave-half, d-quarter
  const int f32io = g_f32io;
  const int zi = zero_vgpr();
  bf16* outh = (bf16*)outv;
  float* outf = (float*)outv;

  __shared__ __align__(16) float sbuf[8192];       // P1 partials / Pr1+P3 tiles / P4 softmax
  __shared__ float part[8][40];
  __shared__ float s_h[512];                       // h_att[eb] for q-dot
  __shared__ float s_aa[664];                      // padded a [0..330) / acum [332..662)
  __shared__ float s_cw[2016];                     // conv weights + bias @1984

  const int eb = bb >> 2, tt0 = (bb & 3) * 75;
  const int da = dwv*128 + lane*2;                 // d-pair (da, da+1)
  const int r0 = h*38, nr = 38 - h;                // energy row range (38 or 37)
  int bn = 0;

  for (int i = tid; i < 1984; i += 512) s_cw[i] = g_cw[i];
  for (int i = tid; i < 32; i += 512) s_cw[1984 + i] = g_cb[i];
  for (int i = tid; i < 664; i += 512) s_aa[i] = 0.f;      // zero pads once
  __syncthreads();

  // per-wave / per-role register preloads
  const int bbu = (bb < 128) ? bb : (bb - 128);
  const int jrow = bbu*4 + dwv;
  float bi, bfg, bgg, bog;
  if (bb < 128) { bi = g_ab[jrow]; bfg = g_ab[512+jrow]; bgg = g_ab[1024+jrow]; bog = g_ab[1536+jrow]; }
  else          { bi = g_db[jrow]; bfg = g_db[512+jrow]; bgg = g_db[1024+jrow]; bog = g_db[1536+jrow]; }
  float prb = 0.f;
  if (bb >= 128 && bb < 148) prb = g_melb[(bb-128)*4 + dwv];
  else if (bb >= 64 && bb < 128) prb = g_b2[(bb-64)*4 + dwv];
  else if (bb >= 192) prb = g_b1[(bb-192)*4 + dwv];

  // ---- Pr0: pre1(0) on blocks 192..255 (waves 0..3) ----
  if (bb >= 192 && tid < 256) {
    float acc = prb;
    const float* mt = g_melT + lane;               // t=0, b = lane
    const float* wr = g_w1 + zi + (size_t)((bb-192)*4 + dwv)*80;
#pragma unroll
    for (int m4 = 0; m4 < 20; ++m4) {
      float4 w = *(const float4*)(wr + m4*4);
      acc = fmaf(w.x, mt[(m4*4+0)*64], acc);
      acc = fmaf(w.y, mt[(m4*4+1)*64], acc);
      acc = fmaf(w.z, mt[(m4*4+2)*64], acc);
      acc = fmaf(w.w, mt[(m4*4+3)*64], acc);
    }
    ast(&g_pm1t4[(bb-192)*256 + lane*4 + dwv], fmaxf(acc, 0.f));
  }
  gbar(++bn, bb, tid);

  // ---- Pr1: mproj rows (half per wave-half) -> registers (packed bf16x2); pre2(0) ----
  unsigned int mpq[38];
  {
    float a1[38], a2[38];
#pragma unroll
    for (int r = 0; r < 38; ++r) { a1[r] = 0.f; a2[r] = 0.f; }
    for (int kt = 0; kt < 16; ++kt) {
      __syncthreads();
      for (int i = tid; i < 75*32; i += 512) {
        int r = i >> 5, kk = i & 31;
        sbuf[i] = g_enc[((size_t)eb*300 + tt0 + r)*512 + kt*32 + kk];
      }
      __syncthreads();
      for (int kk = 0; kk < 32; ++kk) {
        const int k = kt*32 + kk;
        const float2 w = *(const float2*)(g_memwt + (size_t)k*512 + da);
#pragma unroll
        for (int r = 0; r < 38; ++r) {
          const float ev = sbuf[(r0 + r)*32 + kk];   // row 75 slot reads sbuf[2400..2432): garbage, unused
          a1[r] = fmaf(ev, w.x, a1[r]);
          a2[r] = fmaf(ev, w.y, a2[r]);
        }
      }
    }
    const float2 mb = *(const float2*)(g_memb + da);
#pragma unroll
    for (int r = 0; r < 38; ++r)
      mpq[r] = (unsigned)f2us(a1[r] + mb.x) | ((unsigned)f2us(a2[r] + mb.y) << 16);
    if (bb >= 64 && bb < 128 && wv < 4) {            // pre2(0)
      float acc = dotSg(g_pm1t4, g_w2 + zi + (size_t)((bb-64)*4 + dwv)*256, 256, lane, prb);
      ast(&g_pmt4[(bb-64)*256 + lane*4 + dwv], fmaxf(acc, 0.f));
    }
  }
  float Pa[32], Pb[32];
#pragma unroll
  for (int i = 0; i < 8; ++i) {
    float4 u = *(const float4*)(g_pw + (size_t)da*32 + 4*i);
    float4 w = *(const float4*)(g_pw + (size_t)(da+1)*32 + 4*i);
    Pa[4*i] = u.x; Pa[4*i+1] = u.y; Pa[4*i+2] = u.z; Pa[4*i+3] = u.w;
    Pb[4*i] = w.x; Pb[4*i+1] = w.y; Pb[4*i+2] = w.z; Pb[4*i+3] = w.w;
  }
  const float2 vv  = *(const float2*)(g_vw + da);
  const float2 qb2 = *(const float2*)(g_qpb + da);
  const float v1 = vv.x, v2 = vv.y;
  const float vb = g_scal[0];
  gbar(++bn, bb, tid);

  // ================= main loop: 3 barriers/step =================
  for (int t = 0; t <= 500; ++t) {
    const int rp = t & 1, wp = rp ^ 1;

    // ---- P1: att-LSTM(t) [0..127] | dec-LSTM(t-1) [128..255], k-split across 8 waves ----
    if (bb < 128) {
      if (t < 500) {
        float acc[16];
#pragma unroll
        for (int r = 0; r < 16; ++r) acc[r] = 0.f;
        pdot16<768>(g_pmt4, g_awih + zi, bb, wv*32, 32, lane, acc);
        pdot16<768>(g_ctx4, g_awih + zi + 256, bb, wv*64, 64, lane, acc);
        pdot16<512>(g_hatt4 + rp*(512*64), g_awhh + zi, bb, wv*64, 64, lane, acc);
#pragma unroll
        for (int r = 0; r < 16; ++r) sbuf[r*512 + wv*64 + lane] = acc[r];
        __syncthreads();
        if (wv < 4) {
          float s0 = bi, s1 = bfg, s2 = bgg, s3 = bog;
#pragma unroll
          for (int w = 0; w < 8; ++w) {
            s0 += sbuf[(dwv)*512      + w*64 + lane];
            s1 += sbuf[(4 + dwv)*512  + w*64 + lane];
            s2 += sbuf[(8 + dwv)*512  + w*64 + lane];
            s3 += sbuf[(12 + dwv)*512 + w*64 + lane];
          }
          const float c = g_catt[jrow*64 + lane];
          const float cn = sigf(s1)*c + sigf(s0)*tanhf_fast(s2);
          const float hn = sigf(s3)*tanhf_fast(cn);
          g_catt[jrow*64 + lane] = cn;
          ast(&g_hatt4[wp*(512*64) + bb*256 + lane*4 + dwv], hn);
          ast(&g_hattT[lane*512 + jrow], hn);
        }
      }
    } else {
      if (t > 0) {
        float acc[16];
#pragma unroll
        for (int r = 0; r < 16; ++r) acc[r] = 0.f;
        pdot16<1024>(g_hatt4 + rp*(512*64), g_dwih + zi, bbu, wv*64, 64, lane, acc);
        pdot16<1024>(g_ctx4, g_dwih + zi + 512, bbu, wv*64, 64, lane, acc);
        pdot16<512>(g_hdec4 + wp*(512*64), g_dwhh + zi, bbu, wv*64, 64, lane, acc);
#pragma unroll
        for (int r = 0; r < 16; ++r) sbuf[r*512 + wv*64 + lane] = acc[r];
        __syncthreads();
        if (wv < 4) {
          float s0 = bi, s1 = bfg, s2 = bgg, s3 = bog;
#pragma unroll
          for (int w = 0; w < 8; ++w) {
            s0 += sbuf[(dwv)*512      + w*64 + lane];
            s1 += sbuf[(4 + dwv)*512  + w*64 + lane];
            s2 += sbuf[(8 + dwv)*512  + w*64 + lane];
            s3 += sbuf[(12 + dwv)*512 + w*64 + lane];
          }
          const float c = g_cdec[jrow*64 + lane];
          const float cn = sigf(s1)*c + sigf(s0)*tanhf_fast(s2);
          const float hn = sigf(s3)*tanhf_fast(cn);
          g_cdec[jrow*64 + lane] = cn;
          ast(&g_hdec4[rp*(512*64) + (bb-128)*256 + lane*4 + dwv], hn);
        }
      }
    }
    gbar(++bn, bb, tid);

    // ---- P3: energies (all blocks) | pre1(t+1) [192..255] ----
    if (t < 500) {
      s_h[tid] = ald(&g_hattT[eb*512 + tid]);
      if (tid < 300) {
        s_aa[15 + tid]  = ald(&g_a[eb*300 + tid]);
        s_aa[347 + tid] = ald(&g_acum[eb*300 + tid]);
      }
      __syncthreads();
      // conv tile (all 512 threads) into sbuf[0..2400)
      for (int i = tid; i < 75*32; i += 512) {
        const int ttl = i >> 5, c2 = i & 31;
        const int tt = tt0 + ttl;
        float s = s_cw[1984 + c2];
#pragma unroll
        for (int k = 0; k < 31; ++k) {
          s = fmaf(s_cw[c2*62 + k],      s_aa[tt + k], s);
          s = fmaf(s_cw[c2*62 + 31 + k], s_aa[332 + tt + k], s);
        }
        sbuf[i] = s;
      }
      // q-dot: k-half per wave-half
      float q1p = h ? 0.f : qb2.x, q2p = h ? 0.f : qb2.y;
      {
        const int kb = h*256;
#pragma unroll 8
        for (int k = kb; k < kb + 256; k += 2) {
          const float h0 = s_h[k], h1 = s_h[k+1];
          const float2 wA = *(const float2*)(g_qwt + (size_t)k*512 + da);
          const float2 wB = *(const float2*)(g_qwt + (size_t)(k+1)*512 + da);
          q1p = fmaf(wA.x, h0, q1p); q2p = fmaf(wA.y, h0, q2p);
          q1p = fmaf(wB.x, h1, q1p); q2p = fmaf(wB.y, h1, q2p);
        }
      }
      float2* qp = (float2*)(sbuf + 4096);
      qp[wv*64 + lane] = make_float2(q1p, q2p);
      __syncthreads();
      const float2 qA = qp[dwv*64 + lane];
      const float2 qB = qp[(4 + dwv)*64 + lane];
      const float q1 = qA.x + qB.x, q2 = qA.y + qB.y;
      // energy rows r0..r0+nr (row-half per wave-half)
#pragma unroll
      for (int i = 0; i < 38; ++i) {
        if (i < nr) {
          const int gi = r0 + i;
          float s1 = q1 + us2f((unsigned short)(mpq[i] & 0xffffu));
          float s2 = q2 + us2f((unsigned short)(mpq[i] >> 16));
          const float4* cr = (const float4*)(sbuf + gi*32);
#pragma unroll
          for (int c4 = 0; c4 < 8; ++c4) {
            const float4 cv = cr[c4];
            s1 = fmaf(Pa[c4*4+0], cv.x, s1); s2 = fmaf(Pb[c4*4+0], cv.x, s2);
            s1 = fmaf(Pa[c4*4+1], cv.y, s1); s2 = fmaf(Pb[c4*4+1], cv.y, s2);
            s1 = fmaf(Pa[c4*4+2], cv.z, s1); s2 = fmaf(Pb[c4*4+2], cv.z, s2);
            s1 = fmaf(Pa[c4*4+3], cv.w, s1); s2 = fmaf(Pb[c4*4+3], cv.w, s2);
          }
          float p = v1*tanhf_fast(s1) + v2*tanhf_fast(s2);
#pragma unroll
          for (int m = 32; m >= 1; m >>= 1) p += __shfl_xor(p, m, 64);
          if (lane == 0) part[wv][i] = p;
        }
      }
      __syncthreads();
      if (tid < 75) {
        float e;
        if (tid < 38) e = part[0][tid] + part[1][tid] + part[2][tid] + part[3][tid];
        else          e = part[4][tid-38] + part[5][tid-38] + part[6][tid-38] + part[7][tid-38];
        ast(&g_e[eb*300 + tt0 + tid], e + vb);
      }
    }
    if (t <= 498 && bb >= 192 && tid < 256) {     // pre1(t+1)
      float acc = prb;
      const float* mt = g_melT + (size_t)(t+1)*5120 + lane;
      const float* wr = g_w1 + zi + (size_t)((bb-192)*4 + dwv)*80;
#pragma unroll
      for (int m4 = 0; m4 < 20; ++m4) {
        float4 w = *(const float4*)(wr + m4*4);
        acc = fmaf(w.x, mt[(m4*4+0)*64], acc);
        acc = fmaf(w.y, mt[(m4*4+1)*64], acc);
        acc = fmaf(w.z, mt[(m4*4+2)*64], acc);
        acc = fmaf(w.w, mt[(m4*4+3)*64], acc);
      }
      ast(&g_pm1t4[(bb-192)*256 + lane*4 + dwv], fmaxf(acc, 0.f));
    }
    gbar(++bn, bb, tid);

    // ---- P4: softmax+ctx [0..63] | pre2(t+1) [64..127] | mel/stop(t-1) [128..148] ----
    if (t < 500) {
      if (bb < 64) {
        float* pl = sbuf; float* red = sbuf + 304;
        const int b_ = bb;
        const float* Ep = g_e + b_*300;
        const float e1 = (tid < 300) ? ald(Ep + tid) : -3e38f;
        red[tid] = e1; __syncthreads();
        for (int s = 256; s > 0; s >>= 1) { if (tid < s) red[tid] = fmaxf(red[tid], red[tid+s]); __syncthreads(); }
        const float mx = red[0]; __syncthreads();
        const float p1 = (tid < 300) ? __expf(e1 - mx) : 0.f;
        if (tid < 300) pl[tid] = p1;
        red[tid] = p1; __syncthreads();
        for (int s = 256; s > 0; s >>= 1) { if (tid < s) red[tid] += red[tid+s]; __syncthreads(); }
        const float inv = 1.f / red[0];
        if (tid < 300) {
          const float av = p1*inv;
          const float oc = ald(&g_acum[b_*300 + tid]);
          ast(&g_a[b_*300 + tid], av);
          ast(&g_acum[b_*300 + tid], oc + av);
        }
        __syncthreads();
        const float* ep = g_enc + (size_t)(b_*300)*512;
        const int dd = tid;
        float acc = 0.f;
#pragma unroll 8
        for (int tt = 0; tt < 300; ++tt) acc = fmaf(pl[tt], ep[(size_t)tt*512 + dd], acc);
        ast(&g_ctx4[(dd >> 2)*256 + b_*4 + (dd & 3)], acc * inv);
      } else if (bb < 128) {
        if (t <= 498 && wv < 4) {   // pre2(t+1)
          float acc = dotSg(g_pm1t4, g_w2 + zi + (size_t)((bb-64)*4 + dwv)*256, 256, lane, prb);
          ast(&g_pmt4[(bb-64)*256 + lane*4 + dwv], fmaxf(acc, 0.f));
        }
      }
    }
    if (t > 0 && bb >= 128 && bb < 148 && wv < 4) {       // mel(t-1)
      float acc = dotSg(g_hdec4 + rp*(512*64),
                        g_melw + zi + (size_t)((bb-128)*4 + dwv)*512, 512, lane, prb);
      const int m = (bb-128)*4 + dwv;
      const size_t oidx = (size_t)(lane*500 + (t-1))*80 + m;
      if (f32io) outf[oidx] = acc; else outh[oidx] = __float2bfloat16(acc);
    } else if (t > 0 && bb == 148 && tid < 64) {          // stop(t-1)
      float acc = dotSg(g_hdec4 + rp*(512*64), g_stopw + zi, 512, tid, g_scal[1]);
      const size_t oidx = 2560000 + tid*500 + (t-1);
      if (f32io) outf[oidx] = acc; else outh[oidx] = __float2bfloat16(acc);
    }
    gbar(++bn, bb, tid);
  }
}

// ---------------- host ----------------
extern "C" void kernel_launch(void* const* d_in, const int* in_sizes, int n_in,
                              void* d_out, int out_size, void* d_ws, size_t ws_size,
                              hipStream_t stream) {
  (void)d_ws; (void)ws_size; (void)in_sizes; (void)out_size;
  InPtrs P;
  for (int i = 0; i < 28 && i < n_in; ++i) P.p[i] = d_in[i];
  k_convert<<<dim3(2048), dim3(256), 0, stream>>>(P);
  k_dec<<<dim3(NB), dim3(512), 0, stream>>>(d_out);
}